// Round 7
// baseline (9357.433 us; speedup 1.0000x reference)
//
#include <hip/hip_runtime.h>

typedef unsigned short u16;
typedef unsigned int u32;
typedef short v8s __attribute__((ext_vector_type(8)));
typedef float v4f __attribute__((ext_vector_type(4)));
typedef unsigned int v4u __attribute__((ext_vector_type(4)));
typedef unsigned int v2u __attribute__((ext_vector_type(2)));

#define MFMA16 __builtin_amdgcn_mfma_f32_16x16x32_bf16

constexpr int TT = 800;
constexpr int NBLK = 98;   // 32 S0(+attn) + 64 S12 + 2 SM

// aug row (608 bf16 = 1216B): h0(0..511)|win(512..591)|stroke(592..594)|0(595..607)
// slot s holds h0[t: t&3==s], win/stroke[t: t&3==s].
constexpr int AUGB  = 1216;
// aug2 row (1024 bf16 = 2048B): slot s holds h1[t: t&3==s] at [0,1024) and h2[t: t&3==s] at [1024,2048).
constexpr int AUG2B = 2048;

constexpr size_t AUGR_OFF  = 131072;
constexpr size_t AUG2R_OFF = AUGR_OFF + (size_t)4 * 64 * AUGB;     // augr: 311296
constexpr size_t WAT_OFF   = AUG2R_OFF + (size_t)4 * 64 * AUG2B;   // aug2: 524288
constexpr size_t WS_ZERO   = WAT_OFF + (size_t)32 * 512 * 2;       // = 999424

constexpr u32 SMEM_BYTES = 123904;  // S12: aLa 32x1232 + aLb/aLc 32x1040 + zb1/zb2 + biases

// groups: S0 done | S12 done | S12 read-token (h0win slot) | SM read-token
enum { G_S0D = 0, G_S12D = 1, G_S12R = 2, G_SMR = 3 };

__device__ __forceinline__ float bf2f(u16 u) { return __uint_as_float(((u32)u) << 16); }
__device__ __forceinline__ u16 f2bf(float f) {
    u32 x = __float_as_uint(f);
    return (u16)((x + 0x7fffu + ((x >> 16) & 1u)) >> 16);
}
__device__ __forceinline__ short f2bfs(float f) { return (short)f2bf(f); }
__device__ __forceinline__ float sigf(float x) { return 1.f / (1.f + __expf(-x)); }
__device__ __forceinline__ float tanhf2(float x) { return 1.f - 2.f / (1.f + __expf(2.f * x)); }

__device__ __forceinline__ __amdgpu_buffer_rsrc_t mkrsrc(const void* p) {
    return __builtin_amdgcn_make_buffer_rsrc((void*)p, (short)0, -1, 0x00020000);
}
// SC0|SC1: bypass stale L1/L2, coherent at MALL
__device__ __forceinline__ v4u ldu4(__amdgpu_buffer_rsrc_t r, int off) {
    return __builtin_amdgcn_raw_buffer_load_b128(r, off, 0, 17);
}
__device__ __forceinline__ void stq8(__amdgpu_buffer_rsrc_t r, int off, u16 a, u16 b, u16 c, u16 d) {
    v2u t; t[0] = (u32)a | ((u32)b << 16); t[1] = (u32)c | ((u32)d << 16);
    __builtin_amdgcn_raw_buffer_store_b64(t, r, off, 0, 17);
}
__device__ __forceinline__ void stq4(__amdgpu_buffer_rsrc_t r, int off, u16 a, u16 b) {
    u32 t = (u32)a | ((u32)b << 16);
    __builtin_amdgcn_raw_buffer_store_b32(t, r, off, 0, 17);
}

__device__ __forceinline__ v4u mksrd(const void* p) {
    v4u r;
    r[0] = (u32)(size_t)p;
    r[1] = (u32)((size_t)p >> 32);
    r[2] = 0xFFFFFFFFu;
    r[3] = 0x00020000u;
    return r;
}
__device__ __forceinline__ u32 poll_ld(v4u srd, int off) {
    u32 v;
    asm volatile("buffer_load_dword %0, %1, %2, 0 offen sc0 sc1\n\t"
                 "s_waitcnt vmcnt(0)"
                 : "=v"(v) : "v"(off), "s"(srd) : "memory");
    return v;
}

// ---- point-to-point sync (R2-proven: 8 subcounters/mg, 16-lane polls/edge) ---
__device__ __forceinline__ void publish(u32* ctrl, int g, int t, int sub) {
    __hip_atomic_fetch_add(ctrl + g * 4096 + (t & 3) * 1024 + (sub & 15) * 64, 1u,
                           __ATOMIC_RELAXED, __HIP_MEMORY_SCOPE_AGENT);
}
__device__ __forceinline__ void wait4(u32* ctrl,
    int g0, int t0, u32 n0, int m0, int g1, int t1, u32 n1, int m1,
    int g2, int t2, u32 n2, int m2, int g3, int t3, u32 n3, int m3)
{
    if (threadIdx.x < 64) {
        const int lane = threadIdx.x;
        const int cl = lane >> 4, k = lane & 15;
        int g, tt, mb; u32 nn;
        if (cl == 0)      { g = g0; tt = t0; nn = n0; mb = m0; }
        else if (cl == 1) { g = g1; tt = t1; nn = n1; mb = m1; }
        else if (cl == 2) { g = g2; tt = t2; nn = n2; mb = m2; }
        else              { g = g3; tt = t3; nn = n3; mb = m3; }
        const u32 tgt = (g >= 0 && tt >= 0) ? nn * (u32)((tt >> 2) + 1) : 0u;
        const v4u srd = mksrd(ctrl);
        const int boff = (g >= 0) ? (g * 4096 + ((tt & 3)) * 1024 + (mb + (k & 7)) * 64) * 4 : 0;
        int sp = 0;
        for (;;) {
            u32 v = (tgt > 0) ? poll_ld(srd, boff) : 0u;
            v += __shfl_xor(v, 1); v += __shfl_xor(v, 2);
            v += __shfl_xor(v, 4); v += __shfl_xor(v, 8);
            const bool bad = (tgt > 0) && (v < tgt);
            if (__ballot(bad) == 0ull) break;
            if (sp >= 2) __builtin_amdgcn_s_sleep(2);
            else if (sp == 1) __builtin_amdgcn_s_sleep(1);
            sp++;
        }
    }
    __syncthreads();
}

__global__ void wat_init(const float* __restrict__ Wa, u16* __restrict__ WaT) {
    __amdgpu_buffer_rsrc_t r = mkrsrc(WaT);
    for (int idx = blockIdx.x * 256 + threadIdx.x; idx < 32 * 512 / 2; idx += gridDim.x * 256) {
        const int e0 = idx * 2, e1 = e0 + 1;
        const int n0 = e0 >> 9, k0 = e0 & 511;
        const int n1 = e1 >> 9, k1 = e1 & 511;
        const u16 a = (n0 < 30) ? f2bf(Wa[k0 * 30 + n0]) : (u16)0;
        const u16 b = (n1 < 30) ? f2bf(Wa[k1 * 30 + n1]) : (u16)0;
        stq4(r, idx * 4, a, b);
    }
}

__global__ __launch_bounds__(256, 1) void hw_main(
    const float* __restrict__ stroke, const float* __restrict__ charseq, const float* __restrict__ kappa0,
    const float* __restrict__ W0, const float* __restrict__ U0, const float* __restrict__ b0,
    const float* __restrict__ W1, const float* __restrict__ U1, const float* __restrict__ b1,
    const float* __restrict__ W2, const float* __restrict__ U2, const float* __restrict__ b2,
    const float* __restrict__ ba, const float* __restrict__ Wm, const float* __restrict__ bm,
    float* __restrict__ out, char* __restrict__ ws)
{
    extern __shared__ __align__(16) char smem[];
    u32* ctrl = (u32*)ws;
    u16* augr  = (u16*)(ws + AUGR_OFF);
    u16* aug2r = (u16*)(ws + AUG2R_OFF);
    const u16* WaT = (const u16*)(ws + WAT_OFF);

    const int blk = blockIdx.x, tid = threadIdx.x;
    const int wave = tid >> 6, lane = tid & 63;
    const int quad = lane >> 4, l15 = lane & 15;

    if (blk < 32) {
        // ------- S0': lstm0 + attention (skewed). Iteration u (0..TT):
        //   stage h0[u-1] (needed by BOTH U0 matmul and attention) -> LDS
        //   compute h0[u] (u<TT), then attention win[u-1] (u>=1) from the SAME LDS tile.
        //   publish S0D[u] = "h0[u] and win[u-1] visible".
        // deps: S0D[u-1] (self); WAR: S12R[u-4] (h0win slot reuse).
        const int cs = blk & 15, mg = blk >> 4;
        const int mb = mg * 8, sub = mb + (cs & 7);
        __amdgpu_buffer_rsrc_t ra = mkrsrc(augr);
        u16*   aL   = (u16*)smem;                   // 32 rows x 1040B (h0 rows of this mg)
        float* zb   = (float*)(smem + 33280);       // 32 x 132
        float* w0s  = (float*)(smem + 50176);       // 3 x 128
        float* b0s  = (float*)(smem + 51712);       // 128
        u16*   watl = (u16*)(smem + 52224);         // 32 x 520 u16 (WaT)
        float* phis = (float*)(smem + 85504);       // 2 x 80
        u16*   idxs = (u16*)(smem + 86144);         // 2 x 80
        if (tid < 128) {
            const int cn2 = (tid >> 5) * 512 + cs * 32 + (tid & 31);
            b0s[tid] = b0[cn2];
            #pragma unroll
            for (int d = 0; d < 3; d++) w0s[d * 128 + tid] = W0[d * 2048 + cn2];
        }
        {   // WaT -> LDS (32 rows x 1024B; LDS stride 1040)
            #pragma unroll
            for (int c8 = 0; c8 < 8; c8++) {
                const int c = tid + 256 * c8;
                const int row = c >> 6, off = c & 63;
                *(v4u*)((char*)watl + row * 1040 + off * 16) = *(const v4u*)(WaT + row * 512 + off * 8);
            }
        }
        const int batt = mg * 32 + 2 * cs + wave;   // attention batch for waves 0,1
        if (wave < 2) {
            #pragma unroll
            for (int rep = 0; rep < 2; rep++) {
                const int u_ = rep * 64 + lane;
                if (u_ < 80) {
                    int c = 0;
                    #pragma unroll 1
                    for (int cc = 0; cc < 80; cc++)
                        if (charseq[batt * 6400 + u_ * 80 + cc] > 0.5f) c = cc;
                    idxs[wave * 80 + u_] = (u16)c;
                }
            }
        }
        float kap = (wave < 2 && lane < 10) ? kappa0[batt * 10 + lane] : 0.f;
        const float baf = (lane < 30) ? ba[lane] : 0.f;
        const int nn = lane & 31;
        const int k0 = (lane >> 5) * 256;
        const u16* wrow = watl + nn * 520 + k0;
        v8s bw0[16], bw1[16];
        {
            const int cnA = wave * 512 + cs * 32 + l15;
            const int cnB = cnA + 16;
            #pragma unroll
            for (int kc = 0; kc < 16; kc++)
                #pragma unroll
                for (int j = 0; j < 8; j++) {
                    const int k = kc * 32 + quad * 8 + j;
                    bw0[kc][j] = f2bfs(U0[k * 2048 + cnA]);
                    bw1[kc][j] = f2bfs(U0[k * 2048 + cnB]);
                }
        }
        float cst[4] = {0.f, 0.f, 0.f, 0.f};
        const int bpre = mg * 32 + (tid & 31);
        __syncthreads();
        #pragma unroll 1
        for (int u = 0; u <= TT; u++) {
            float xx0 = 0.f, xx1 = 0.f, xx2 = 0.f;
            if (u < TT) {
                xx0 = stroke[(bpre * TT + u) * 3 + 0];
                xx1 = stroke[(bpre * TT + u) * 3 + 1];
                xx2 = stroke[(bpre * TT + u) * 3 + 2];
            }
            float sx0 = 0.f, sx1 = 0.f;
            if (u >= 1 && wave < 2) {
                if (lane == 40) { sx0 = stroke[(batt * TT + u - 1) * 3 + 0]; sx1 = stroke[(batt * TT + u - 1) * 3 + 1]; }
                else if (lane == 41) { sx0 = stroke[(batt * TT + u - 1) * 3 + 2]; }
            }
            wait4(ctrl, G_S0D, u - 1, 32, mb, G_S12R, u - 4, 64, mb, -1, 0, 0, 0, -1, 0, 0, 0);
            {   // stage h0[u-1] (slot (u-1)&3, rows of this mg, bytes [0,1024))
                const int base = (((u + 3) & 3) * 64 + mg * 32) * AUGB;
                #pragma unroll
                for (int c8 = 0; c8 < 8; c8++) {
                    const int c = tid + 256 * c8;
                    const int row = c >> 6, off = c & 63;
                    v4u d = ldu4(ra, base + row * AUGB + off * 16);
                    *(v4u*)((char*)aL + row * 1040 + off * 16) = d;
                }
            }
            __syncthreads();
            if (u < TT) {
                v4f c0a = {0,0,0,0}, c0b = {0,0,0,0}, c1a = {0,0,0,0}, c1b = {0,0,0,0};
                const int xo = quad * 16;
                #pragma unroll
                for (int kc = 0; kc < 16; kc++) {
                    v8s x0 = *(const v8s*)((const char*)aL + l15 * 1040 + kc * 64 + xo);
                    v8s x1 = *(const v8s*)((const char*)aL + (16 + l15) * 1040 + kc * 64 + xo);
                    c0a = MFMA16(x0, bw0[kc], c0a, 0, 0, 0);
                    c1a = MFMA16(x0, bw1[kc], c1a, 0, 0, 0);
                    c0b = MFMA16(x1, bw0[kc], c0b, 0, 0, 0);
                    c1b = MFMA16(x1, bw1[kc], c1b, 0, 0, 0);
                }
                const int n0 = wave * 32 + l15, n1 = n0 + 16;
                #pragma unroll
                for (int r = 0; r < 4; r++) {
                    zb[(quad * 4 + r) * 132 + n0] = c0a[r];
                    zb[(quad * 4 + r) * 132 + n1] = c1a[r];
                    zb[(16 + quad * 4 + r) * 132 + n0] = c0b[r];
                    zb[(16 + quad * 4 + r) * 132 + n1] = c1b[r];
                }
            }
            __syncthreads();
            if (u < TT) {   // epilogue: h0[u], 32 rows x 32 cols, 4 cells/thread
                const int bl = tid & 31, jj = tid >> 5;
                const int b = mg * 32 + bl;
                u16 hv[4];
                #pragma unroll
                for (int m = 0; m < 4; m++) {
                    const int j = jj * 4 + m;
                    float z[4];
                    #pragma unroll
                    for (int g = 0; g < 4; g++) {
                        const int n = g * 32 + j;
                        z[g] = zb[bl * 132 + n] + b0s[n] + xx0 * w0s[n] + xx1 * w0s[128 + n] + xx2 * w0s[256 + n];
                    }
                    const float cc = sigf(z[1]) * cst[m] + sigf(z[0]) * tanhf2(z[2]);
                    cst[m] = cc;
                    hv[m] = f2bf(sigf(z[3]) * tanhf2(cc));
                }
                stq8(ra, ((u & 3) * 64 + b) * AUGB + (cs * 32 + jj * 4) * 2, hv[0], hv[1], hv[2], hv[3]);
            }
            if (u >= 1) {
                // ---- attention for t=u-1 from the staged aL (h0[u-1]) ----
                if (wave < 2) {
                    float acc = 0.f;
                    #pragma unroll
                    for (int kk = 0; kk < 32; kk++) {
                        v8s hv = *(const v8s*)((const char*)aL + (2 * cs + wave) * 1040 + (k0 + kk * 8) * 2);
                        v8s wv = *(const v8s*)(wrow + kk * 8);
                        #pragma unroll
                        for (int e = 0; e < 8; e++) acc += bf2f((u16)hv[e]) * bf2f((u16)wv[e]);
                    }
                    acc += __shfl_xor(acc, 32);
                    const float abk = __expf(acc + baf);
                    const float kofv = __shfl(abk, 20 + (lane < 10 ? lane : 0));
                    if (lane < 10) kap += kofv;
                    const float u1f = (float)lane;
                    float p1 = 0.f, p2 = 0.f;
                    #pragma unroll
                    for (int kk = 0; kk < 10; kk++) {
                        const float al = __shfl(abk, kk);
                        const float be = __shfl(abk, 10 + kk);
                        const float kp = __shfl(kap, kk);
                        const float d1 = kp - u1f, d2 = kp - (u1f + 64.f);
                        p1 += al * __expf(-be * d1 * d1);
                        p2 += al * __expf(-be * d2 * d2);
                    }
                    phis[wave * 80 + lane] = p1;
                    if (lane < 16) phis[wave * 80 + 64 + lane] = p2;
                }
                __syncthreads();
                if (wave < 2) {
                    const int db = ((((u - 1) & 3) * 64 + batt) * AUGB) + 512 * 2;
                    if (lane < 40) {
                        const int c0 = 2 * lane;
                        float w0 = 0.f, w1 = 0.f;
                        #pragma unroll 1
                        for (int uu = 0; uu < 80; uu++) {
                            const float pv = phis[wave * 80 + uu];
                            const int ix = (int)idxs[wave * 80 + uu];
                            w0 += (ix == c0)     ? pv : 0.f;
                            w1 += (ix == c0 + 1) ? pv : 0.f;
                        }
                        stq4(ra, db + c0 * 2, f2bf(w0), f2bf(w1));
                    } else if (lane == 40) {
                        stq4(ra, db + 80 * 2, f2bf(sx0), f2bf(sx1));
                    } else if (lane == 41) {
                        stq4(ra, db + 82 * 2, f2bf(sx0), (u16)0);
                    }
                }
            }
            __syncthreads();   // drain all stores
            if (tid == 0) publish(ctrl, G_S0D, u, sub);
        }
    } else if (blk < 96) {
        // ------- S12: lstm1[tau] + lstm2[tau-1] fused. 64 blocks (32/mg), 16 cols each layer.
        // Iteration tau (0..TT): ONE wait {S0D[tau+1], S12D[tau-1], SMR[tau-4]},
        // ONE staging burst {h0win[tau], h1[tau-1] (shared by U1-part and W2-part!), h2[tau-2]},
        // MFMAs for both layers, both epilogues, ONE drain, publish S12D[tau].
        // WAR audit: aug2 slot reuse is covered by the S12D[tau-1] self-wait (all peers >= tau);
        // h0win slot reuse by S0 is covered by the S12R token.
        const int q = blk - 32, cs = q >> 1, mg = q & 1;
        const int mb = mg * 8, sub = mb + (cs & 7);
        __amdgpu_buffer_rsrc_t ra = mkrsrc(augr);
        __amdgpu_buffer_rsrc_t r2 = mkrsrc(aug2r);
        u16*   aLa = (u16*)smem;                    // 32 x 1232B (h0|win|stroke|0, 608 elems; 16B pad)
        u16*   aLb = (u16*)(smem + 39424);          // 32 x 1040B (h1[tau-1])
        u16*   aLc = (u16*)(smem + 72704);          // 32 x 1040B (h2[tau-2])
        float* zb1 = (float*)(smem + 105984);       // 32 x 68
        float* zb2 = (float*)(smem + 114688);       // 32 x 68
        float* b1s = (float*)(smem + 123392);       // 64
        float* b2s = (float*)(smem + 123648);       // 64
        if (tid < 64) {
            b1s[tid] = b1[(tid >> 4) * 512 + cs * 16 + (tid & 15)];
            b2s[tid] = b2[(tid >> 4) * 512 + cs * 16 + (tid & 15)];
        }
        v8s bw1[35], bw2[32];
        {
            const int cn = wave * 512 + cs * 16 + l15;
            #pragma unroll
            for (int kc = 0; kc < 35; kc++)
                #pragma unroll
                for (int j = 0; j < 8; j++) {
                    const int k = kc * 32 + quad * 8 + j;
                    short v = 0;
                    if (kc < 19) { if (k < 595) v = f2bfs(W1[k * 2048 + cn]); }
                    else v = f2bfs(U1[(k - 608) * 2048 + cn]);
                    bw1[kc][j] = v;
                }
            #pragma unroll
            for (int kc = 0; kc < 32; kc++)
                #pragma unroll
                for (int j = 0; j < 8; j++) {
                    const int k = kc * 32 + quad * 8 + j;
                    bw2[kc][j] = (kc < 16) ? f2bfs(W2[k * 2048 + cn]) : f2bfs(U2[(k - 512) * 2048 + cn]);
                }
        }
        float cst1[2] = {0.f, 0.f}, cst2[2] = {0.f, 0.f};
        __syncthreads();
        #pragma unroll 1
        for (int tau = 0; tau <= TT; tau++) {
            const int s0t = (tau < TT) ? tau + 1 : TT;
            wait4(ctrl, G_S0D, s0t, 32, mb, G_S12D, tau - 1, 64, mb, G_SMR, tau - 4, 2, mb, -1, 0, 0, 0);
            {   // ONE staging burst (max MLP): aLa 2432 + aLb 2048 + aLc 2048 chunks
                const int base_a = ((tau & 3) * 64 + mg * 32) * AUGB;
                const int base_b = (((tau + 3) & 3) * 64 + mg * 32) * AUG2B;          // h1[tau-1]
                const int base_c = (((tau + 2) & 3) * 64 + mg * 32) * AUG2B + 1024;   // h2[tau-2]
                #pragma unroll
                for (int c10 = 0; c10 < 10; c10++) {
                    const int c = tid + 256 * c10;
                    if (c < 2432) {
                        const int row = c / 76, off = c - row * 76;
                        v4u d = ldu4(ra, base_a + row * AUGB + off * 16);
                        *(v4u*)((char*)aLa + row * 1232 + off * 16) = d;
                    }
                }
                #pragma unroll
                for (int c8 = 0; c8 < 8; c8++) {
                    const int c = tid + 256 * c8;
                    const int row = c >> 6, off = c & 63;
                    v4u d = ldu4(r2, base_b + row * AUG2B + off * 16);
                    *(v4u*)((char*)aLb + row * 1040 + off * 16) = d;
                }
                #pragma unroll
                for (int c8 = 0; c8 < 8; c8++) {
                    const int c = tid + 256 * c8;
                    const int row = c >> 6, off = c & 63;
                    v4u d = ldu4(r2, base_c + row * AUG2B + off * 16);
                    *(v4u*)((char*)aLc + row * 1040 + off * 16) = d;
                }
            }
            __syncthreads();
            if (tid == 0) publish(ctrl, G_S12R, tau, sub);
            v4f c0 = {0,0,0,0}, c1 = {0,0,0,0};   // layer1 acc
            v4f d0 = {0,0,0,0}, d1 = {0,0,0,0};   // layer2 acc
            const int xo = quad * 16;
            // shared-operand block: aLb feeds L1's U1-part AND L2's W2-part (4 indep chains)
            #pragma unroll
            for (int kc = 0; kc < 16; kc++) {
                v8s x0 = *(const v8s*)((const char*)aLb + l15 * 1040 + kc * 64 + xo);
                v8s x1 = *(const v8s*)((const char*)aLb + (16 + l15) * 1040 + kc * 64 + xo);
                c0 = MFMA16(x0, bw1[19 + kc], c0, 0, 0, 0);
                d0 = MFMA16(x0, bw2[kc], d0, 0, 0, 0);
                c1 = MFMA16(x1, bw1[19 + kc], c1, 0, 0, 0);
                d1 = MFMA16(x1, bw2[kc], d1, 0, 0, 0);
            }
            #pragma unroll
            for (int kc = 0; kc < 19; kc++) {
                v8s y0 = *(const v8s*)((const char*)aLa + l15 * 1232 + kc * 64 + xo);
                v8s y1 = *(const v8s*)((const char*)aLa + (16 + l15) * 1232 + kc * 64 + xo);
                c0 = MFMA16(y0, bw1[kc], c0, 0, 0, 0);
                c1 = MFMA16(y1, bw1[kc], c1, 0, 0, 0);
            }
            #pragma unroll
            for (int kc = 0; kc < 16; kc++) {
                v8s z0 = *(const v8s*)((const char*)aLc + l15 * 1040 + kc * 64 + xo);
                v8s z1 = *(const v8s*)((const char*)aLc + (16 + l15) * 1040 + kc * 64 + xo);
                d0 = MFMA16(z0, bw2[16 + kc], d0, 0, 0, 0);
                d1 = MFMA16(z1, bw2[16 + kc], d1, 0, 0, 0);
            }
            #pragma unroll
            for (int r = 0; r < 4; r++) {
                zb1[(quad * 4 + r) * 68 + wave * 17 + l15] = c0[r];
                zb1[(16 + quad * 4 + r) * 68 + wave * 17 + l15] = c1[r];
                zb2[(quad * 4 + r) * 68 + wave * 17 + l15] = d0[r];
                zb2[(16 + quad * 4 + r) * 68 + wave * 17 + l15] = d1[r];
            }
            __syncthreads();
            {
                const int bl = tid & 31, jj = tid >> 5;
                const int b = mg * 32 + bl;
                if (tau < TT) {   // L1 epilogue -> h1[tau], slot tau&3 [0,1024)
                    u16 hv[2];
                    #pragma unroll
                    for (int m = 0; m < 2; m++) {
                        const int j = jj * 2 + m;
                        float z[4];
                        #pragma unroll
                        for (int g = 0; g < 4; g++)
                            z[g] = zb1[bl * 68 + g * 17 + j] + b1s[g * 16 + j];
                        const float cc = sigf(z[1]) * cst1[m] + sigf(z[0]) * tanhf2(z[2]);
                        cst1[m] = cc;
                        hv[m] = f2bf(sigf(z[3]) * tanhf2(cc));
                    }
                    stq4(r2, ((tau & 3) * 64 + b) * AUG2B + (cs * 16 + jj * 2) * 2, hv[0], hv[1]);
                }
                if (tau >= 1) {   // L2 epilogue -> h2[tau-1], slot (tau-1)&3 [1024,2048)
                    u16 hv[2];
                    #pragma unroll
                    for (int m = 0; m < 2; m++) {
                        const int j = jj * 2 + m;
                        float z[4];
                        #pragma unroll
                        for (int g = 0; g < 4; g++)
                            z[g] = zb2[bl * 68 + g * 17 + j] + b2s[g * 16 + j];
                        const float cc = sigf(z[1]) * cst2[m] + sigf(z[0]) * tanhf2(z[2]);
                        cst2[m] = cc;
                        hv[m] = f2bf(sigf(z[3]) * tanhf2(cc));
                    }
                    stq4(r2, (((tau + 3) & 3) * 64 + b) * AUG2B + 1024 + (cs * 16 + jj * 2) * 2, hv[0], hv[1]);
                }
            }
            __syncthreads();   // drain
            if (tid == 0) publish(ctrl, G_S12D, tau, sub);
        }
    } else {
        // ------- SM: MDN head. deps: S12D[t+1] (h2[t] visible). 2 blocks.
        const int mgs = blk - 96;
        const int mb = mgs * 8;
        __amdgpu_buffer_rsrc_t r2 = mkrsrc(aug2r);
        u16*   aL = (u16*)smem;                    // 32 rows x 1040B
        float* zb = (float*)(smem + 33280);        // 32 x 132
        v8s bw0[16], bw1[16];
        {
            const int nA = wave * 32 + l15, nB = nA + 16;
            #pragma unroll
            for (int kc = 0; kc < 16; kc++)
                #pragma unroll
                for (int j = 0; j < 8; j++) {
                    const int k = kc * 32 + quad * 8 + j;
                    bw0[kc][j] = (nA < 121) ? f2bfs(Wm[k * 121 + nA]) : (short)0;
                    bw1[kc][j] = (nB < 121) ? f2bfs(Wm[k * 121 + nB]) : (short)0;
                }
        }
        __syncthreads();
        #pragma unroll 1
        for (int t = 0; t < TT; t++) {
            wait4(ctrl, G_S12D, t + 1, 64, mb, -1, 0, 0, 0, -1, 0, 0, 0, -1, 0, 0, 0);
            {   // stage h2[t] (slot t&3, [1024,2048))
                const int base = ((t & 3) * 64 + mgs * 32) * AUG2B + 1024;
                #pragma unroll
                for (int c8 = 0; c8 < 8; c8++) {
                    const int c = tid + 256 * c8;
                    const int row = c >> 6, off = c & 63;
                    v4u d = ldu4(r2, base + row * AUG2B + off * 16);
                    *(v4u*)((char*)aL + row * 1040 + off * 16) = d;
                }
            }
            __syncthreads();
            if (tid == 0) publish(ctrl, G_SMR, t, mb);
            v4f c0a = {0,0,0,0}, c0b = {0,0,0,0}, c1a = {0,0,0,0}, c1b = {0,0,0,0};
            const int xo = quad * 16;
            #pragma unroll
            for (int kc = 0; kc < 16; kc++) {
                v8s x0 = *(const v8s*)((const char*)aL + l15 * 1040 + kc * 64 + xo);
                v8s x1 = *(const v8s*)((const char*)aL + (16 + l15) * 1040 + kc * 64 + xo);
                c0a = MFMA16(x0, bw0[kc], c0a, 0, 0, 0);
                c1a = MFMA16(x0, bw1[kc], c1a, 0, 0, 0);
                c0b = MFMA16(x1, bw0[kc], c0b, 0, 0, 0);
                c1b = MFMA16(x1, bw1[kc], c1b, 0, 0, 0);
            }
            const int n0 = wave * 32 + l15, n1 = n0 + 16;
            #pragma unroll
            for (int r = 0; r < 4; r++) {
                zb[(quad * 4 + r) * 132 + n0] = c0a[r];
                zb[(quad * 4 + r) * 132 + n1] = c1a[r];
                zb[(16 + quad * 4 + r) * 132 + n0] = c0b[r];
                zb[(16 + quad * 4 + r) * 132 + n1] = c1b[r];
            }
            __syncthreads();
            {
                const int b8 = tid >> 3, g8 = tid & 7;
                const int b = mgs * 32 + b8;
                const float* zr = zb + b8 * 132;
                float* orow = out + ((size_t)(b * TT + t)) * 121;
                if (g8 == 0) {
                    orow[0] = sigf(-(zr[0] + bm[0]));
                    float mx = -1e30f;
                    float zv[20];
                    #pragma unroll 1
                    for (int nl = 1; nl <= 20; nl++) { zv[nl - 1] = zr[nl] + bm[nl]; mx = fmaxf(mx, zv[nl - 1]); }
                    float ss = 0.f;
                    #pragma unroll 1
                    for (int nl = 0; nl < 20; nl++) { zv[nl] = __expf(zv[nl] - mx); ss += zv[nl]; }
                    const float inv = 1.f / ss;
                    #pragma unroll 1
                    for (int nl = 0; nl < 20; nl++) orow[nl + 1] = zv[nl] * inv;
                } else if (g8 <= 2) {
                    const int s0 = 21 + (g8 - 1) * 20;
                    #pragma unroll 1
                    for (int nl = s0; nl < s0 + 20; nl++) orow[nl] = zr[nl] + bm[nl];
                } else if (g8 <= 4) {
                    const int s0 = 61 + (g8 - 3) * 20;
                    #pragma unroll 1
                    for (int nl = s0; nl < s0 + 20; nl++) orow[nl] = __expf(zr[nl] + bm[nl]);
                } else if (g8 <= 6) {
                    const int s0 = 101 + (g8 - 5) * 10;
                    #pragma unroll 1
                    for (int nl = s0; nl < s0 + 10; nl++) orow[nl] = tanhf2(zr[nl] + bm[nl]);
                }
            }
            __syncthreads();
        }
    }
}

extern "C" void kernel_launch(void* const* d_in, const int* in_sizes, int n_in,
                              void* d_out, int out_size, void* d_ws, size_t ws_size,
                              hipStream_t stream) {
    const float* stroke  = (const float*)d_in[0];
    const float* charseq = (const float*)d_in[1];
    const float* kappa0  = (const float*)d_in[2];
    const float* W0 = (const float*)d_in[3];
    const float* U0 = (const float*)d_in[4];
    const float* b0 = (const float*)d_in[5];
    const float* W1 = (const float*)d_in[6];
    const float* U1 = (const float*)d_in[7];
    const float* b1 = (const float*)d_in[8];
    const float* W2 = (const float*)d_in[9];
    const float* U2 = (const float*)d_in[10];
    const float* b2 = (const float*)d_in[11];
    const float* Wa = (const float*)d_in[12];
    const float* ba = (const float*)d_in[13];
    const float* Wm = (const float*)d_in[14];
    const float* bm = (const float*)d_in[15];
    char* ws = (char*)d_ws;

    static bool attr_done = false;
    if (!attr_done) {
        hipFuncSetAttribute((const void*)hw_main,
                            hipFuncAttributeMaxDynamicSharedMemorySize, SMEM_BYTES);
        attr_done = true;
    }

    hipMemsetAsync(d_ws, 0, WS_ZERO, stream);
    wat_init<<<8, 256, 0, stream>>>(Wa, (u16*)(ws + WAT_OFF));
    hw_main<<<NBLK, 256, SMEM_BYTES, stream>>>(stroke, charseq, kappa0, W0, U0, b0,
                                               W1, U1, b1, W2, U2, b2, ba, Wm, bm,
                                               (float*)d_out, ws);
}

// Round 8
// 8622.392 us; speedup vs baseline: 1.0852x; 1.0852x over previous
//
#include <hip/hip_runtime.h>

typedef unsigned short u16;
typedef unsigned int u32;
typedef short v8s __attribute__((ext_vector_type(8)));
typedef float v4f __attribute__((ext_vector_type(4)));
typedef unsigned int v4u __attribute__((ext_vector_type(4)));
typedef unsigned int v2u __attribute__((ext_vector_type(2)));

#define MFMA16 __builtin_amdgcn_mfma_f32_16x16x32_bf16

constexpr int TT = 800;
constexpr int NBLK = 178;

// ---- packed, block-owned interchange buffers (no shared cache lines) --------
// H0 : [4 slots][mg:2][cs:16][row:32][32 cols] bf16 -> 2KB chunk per S0 block
// WIN: [4 slots][mg:2][row:32][96 cols (80 win + 3 stroke + 13 zero), pad 128] -> 256B row, one wave writes it
// H1 : [4 slots][mg:2][cs:32][row:32][16 cols] bf16 -> 1KB chunk per S1 block
// H2 : same shape as H1, written by S2
constexpr size_t H0_OFF  = 131072;                       // ctrl = [0,131072)
constexpr size_t WIN_OFF = H0_OFF  + (size_t)4 * 2 * 16 * 2048;   // +262144
constexpr size_t H1_OFF  = WIN_OFF + (size_t)4 * 2 * 32 * 256;    // +65536
constexpr size_t H2_OFF  = H1_OFF  + (size_t)4 * 2 * 32 * 1024;   // +262144
constexpr size_t WAT_OFF = H2_OFF  + (size_t)4 * 2 * 32 * 1024;   // +262144
constexpr size_t WS_ZERO = WAT_OFF + (size_t)32 * 512 * 2;        // = 1015808

constexpr u32 SMEM_BYTES = 81920;   // max = S1: 32x2256 aL + zb + b1s

enum { G_S0D = 0, G_SAD = 1, G_S1D = 2, G_S2D = 3, G_S1R = 4, G_SAR = 5, G_S2R = 6, G_SMR = 7 };

__device__ __forceinline__ float bf2f(u16 u) { return __uint_as_float(((u32)u) << 16); }
__device__ __forceinline__ u16 f2bf(float f) {
    u32 x = __float_as_uint(f);
    return (u16)((x + 0x7fffu + ((x >> 16) & 1u)) >> 16);
}
__device__ __forceinline__ short f2bfs(float f) { return (short)f2bf(f); }
__device__ __forceinline__ float sigf(float x) { return 1.f / (1.f + __expf(-x)); }
__device__ __forceinline__ float tanhf2(float x) { return 1.f - 2.f / (1.f + __expf(2.f * x)); }

__device__ __forceinline__ __amdgpu_buffer_rsrc_t mkrsrc(const void* p) {
    return __builtin_amdgcn_make_buffer_rsrc((void*)p, (short)0, -1, 0x00020000);
}
// SC0|SC1 load: bypass stale L1/L2, coherent at MALL
__device__ __forceinline__ v4u ldu4(__amdgpu_buffer_rsrc_t r, int off) {
    return __builtin_amdgcn_raw_buffer_load_b128(r, off, 0, 17);
}
// SC1 write-through stores
__device__ __forceinline__ void stq8(__amdgpu_buffer_rsrc_t r, int off, u16 a, u16 b, u16 c, u16 d) {
    v2u t; t[0] = (u32)a | ((u32)b << 16); t[1] = (u32)c | ((u32)d << 16);
    __builtin_amdgcn_raw_buffer_store_b64(t, r, off, 0, 17);
}
__device__ __forceinline__ void stq4(__amdgpu_buffer_rsrc_t r, int off, u16 a, u16 b) {
    u32 t = (u32)a | ((u32)b << 16);
    __builtin_amdgcn_raw_buffer_store_b32(t, r, off, 0, 17);
}

// manual SRD for inline-asm poll loads
__device__ __forceinline__ v4u mksrd(const void* p) {
    v4u r;
    r[0] = (u32)(size_t)p;
    r[1] = (u32)((size_t)p >> 32);
    r[2] = 0xFFFFFFFFu;
    r[3] = 0x00020000u;
    return r;
}
__device__ __forceinline__ u32 poll_ld(v4u srd, int off) {
    u32 v;
    asm volatile("buffer_load_dword %0, %1, %2, 0 offen sc0 sc1\n\t"
                 "s_waitcnt vmcnt(0)"
                 : "=v"(v) : "v"(off), "s"(srd) : "memory");
    return v;
}

// ---- point-to-point sync (R2-proven: 8 subcounters/mg, 16-lane polls/edge) --
__device__ __forceinline__ void publish(u32* ctrl, int g, int t, int sub) {
    __hip_atomic_fetch_add(ctrl + g * 4096 + (t & 3) * 1024 + (sub & 15) * 64, 1u,
                           __ATOMIC_RELAXED, __HIP_MEMORY_SCOPE_AGENT);
}
__device__ __forceinline__ void wait4(u32* ctrl,
    int g0, int t0, u32 n0, int m0, int g1, int t1, u32 n1, int m1,
    int g2, int t2, u32 n2, int m2, int g3, int t3, u32 n3, int m3)
{
    if (threadIdx.x < 64) {
        const int lane = threadIdx.x;
        const int cl = lane >> 4, k = lane & 15;
        int g, tt, mb; u32 nn;
        if (cl == 0)      { g = g0; tt = t0; nn = n0; mb = m0; }
        else if (cl == 1) { g = g1; tt = t1; nn = n1; mb = m1; }
        else if (cl == 2) { g = g2; tt = t2; nn = n2; mb = m2; }
        else              { g = g3; tt = t3; nn = n3; mb = m3; }
        const u32 tgt = (g >= 0 && tt >= 0) ? nn * (u32)((tt >> 2) + 1) : 0u;
        const v4u srd = mksrd(ctrl);
        const int boff = (g >= 0) ? (g * 4096 + ((tt & 3)) * 1024 + (mb + (k & 7)) * 64) * 4 : 0;
        int sp = 0;
        for (;;) {
            u32 v = (tgt > 0) ? poll_ld(srd, boff) : 0u;
            v += __shfl_xor(v, 1); v += __shfl_xor(v, 2);
            v += __shfl_xor(v, 4); v += __shfl_xor(v, 8);
            const bool bad = (tgt > 0) && (v < tgt);
            if (__ballot(bad) == 0ull) break;
            if (sp >= 2) __builtin_amdgcn_s_sleep(2);
            else if (sp == 1) __builtin_amdgcn_s_sleep(1);
            sp++;
        }
    }
    __syncthreads();
}

__global__ void wat_init(const float* __restrict__ Wa, u16* __restrict__ WaT) {
    __amdgpu_buffer_rsrc_t r = mkrsrc(WaT);
    for (int idx = blockIdx.x * 256 + threadIdx.x; idx < 32 * 512 / 2; idx += gridDim.x * 256) {
        const int e0 = idx * 2, e1 = e0 + 1;
        const int n0 = e0 >> 9, k0 = e0 & 511;
        const int n1 = e1 >> 9, k1 = e1 & 511;
        const u16 a = (n0 < 30) ? f2bf(Wa[k0 * 30 + n0]) : (u16)0;
        const u16 b = (n1 < 30) ? f2bf(Wa[k1 * 30 + n1]) : (u16)0;
        stq4(r, idx * 4, a, b);
    }
}

__global__ __launch_bounds__(256, 1) void hw_main(
    const float* __restrict__ stroke, const float* __restrict__ charseq, const float* __restrict__ kappa0,
    const float* __restrict__ W0, const float* __restrict__ U0, const float* __restrict__ b0,
    const float* __restrict__ W1, const float* __restrict__ U1, const float* __restrict__ b1,
    const float* __restrict__ W2, const float* __restrict__ U2, const float* __restrict__ b2,
    const float* __restrict__ ba, const float* __restrict__ Wm, const float* __restrict__ bm,
    float* __restrict__ out, char* __restrict__ ws)
{
    extern __shared__ __align__(16) char smem[];
    u32* ctrl = (u32*)ws;
    u16* h0b  = (u16*)(ws + H0_OFF);
    u16* winb = (u16*)(ws + WIN_OFF);
    u16* h1b  = (u16*)(ws + H1_OFF);
    u16* h2b  = (u16*)(ws + H2_OFF);
    const u16* WaT = (const u16*)(ws + WAT_OFF);

    const int blk = blockIdx.x, tid = threadIdx.x;
    const int wave = tid >> 6, lane = tid & 63;
    const int quad = lane >> 4, l15 = lane & 15;

    if (blk < 32) {
        // ------- S0: lstm0. deps: S0d[t-1]; WAR: S1r[t-4], SAr[t-4] (same mg).
        const int cs = blk & 15, mg = blk >> 4;
        const int mb = mg * 8, sub = mb + (cs & 7);
        __amdgpu_buffer_rsrc_t rh0 = mkrsrc(h0b);
        u16*   aL  = (u16*)smem;                   // 32 rows x 1040B
        float* zb  = (float*)(smem + 33280);       // 32 x 132
        float* w0s = (float*)(smem + 50176);       // 3 x 128
        float* b0s = (float*)(smem + 51712);       // 128
        if (tid < 128) {
            const int cn2 = (tid >> 5) * 512 + cs * 32 + (tid & 31);
            b0s[tid] = b0[cn2];
            #pragma unroll
            for (int d = 0; d < 3; d++) w0s[d * 128 + tid] = W0[d * 2048 + cn2];
        }
        v8s bw0[16], bw1[16];
        {
            const int cnA = wave * 512 + cs * 32 + l15;
            const int cnB = cnA + 16;
            #pragma unroll
            for (int kc = 0; kc < 16; kc++)
                #pragma unroll
                for (int j = 0; j < 8; j++) {
                    const int k = kc * 32 + quad * 8 + j;
                    bw0[kc][j] = f2bfs(U0[k * 2048 + cnA]);
                    bw1[kc][j] = f2bfs(U0[k * 2048 + cnB]);
                }
        }
        float cst[4] = {0.f, 0.f, 0.f, 0.f};
        const int bpre = mg * 32 + (tid & 31);
        __syncthreads();
        #pragma unroll 1
        for (int t = 0; t < TT; t++) {
            const float xx0 = stroke[(bpre * TT + t) * 3 + 0];
            const float xx1 = stroke[(bpre * TT + t) * 3 + 1];
            const float xx2 = stroke[(bpre * TT + t) * 3 + 2];
            wait4(ctrl, G_S0D, t - 1, 32, mb, G_S1R, t - 4, 64, mb, G_SAR, t - 4, 16, mb, -1, 0, 0, 0);
            {   // stage h0[t-1]: 16 packed 2KB chunks (slot (t-1)&3, this mg)
                const int base = ((((t + 3) & 3) * 2 + mg) * 16) * 2048;
                #pragma unroll
                for (int c8 = 0; c8 < 8; c8++) {
                    const int c = tid + 256 * c8;
                    const int cs_ = c >> 7, w = c & 127;
                    const int row = w >> 2, col16 = w & 3;
                    v4u d = ldu4(rh0, base + cs_ * 2048 + w * 16);
                    *(v4u*)((char*)aL + row * 1040 + cs_ * 64 + col16 * 16) = d;
                }
            }
            __syncthreads();
            v4f c0a = {0,0,0,0}, c0b = {0,0,0,0}, c1a = {0,0,0,0}, c1b = {0,0,0,0};
            const int xo = quad * 16;
            #pragma unroll
            for (int kc = 0; kc < 16; kc++) {
                v8s x0 = *(const v8s*)((const char*)aL + l15 * 1040 + kc * 64 + xo);
                v8s x1 = *(const v8s*)((const char*)aL + (16 + l15) * 1040 + kc * 64 + xo);
                c0a = MFMA16(x0, bw0[kc], c0a, 0, 0, 0);
                c1a = MFMA16(x0, bw1[kc], c1a, 0, 0, 0);
                c0b = MFMA16(x1, bw0[kc], c0b, 0, 0, 0);
                c1b = MFMA16(x1, bw1[kc], c1b, 0, 0, 0);
            }
            const int n0 = wave * 32 + l15, n1 = n0 + 16;
            #pragma unroll
            for (int r = 0; r < 4; r++) {
                zb[(quad * 4 + r) * 132 + n0] = c0a[r];
                zb[(quad * 4 + r) * 132 + n1] = c1a[r];
                zb[(16 + quad * 4 + r) * 132 + n0] = c0b[r];
                zb[(16 + quad * 4 + r) * 132 + n1] = c1b[r];
            }
            __syncthreads();
            {   // epilogue: write h0[t] into OWN 2KB chunk (full lines, single writer)
                const int bl = tid & 31, jj = tid >> 5;
                u16 hv[4];
                #pragma unroll
                for (int m = 0; m < 4; m++) {
                    const int j = jj * 4 + m;
                    float z[4];
                    #pragma unroll
                    for (int g = 0; g < 4; g++) {
                        const int n = g * 32 + j;
                        z[g] = zb[bl * 132 + n] + b0s[n] + xx0 * w0s[n] + xx1 * w0s[128 + n] + xx2 * w0s[256 + n];
                    }
                    const float cc = sigf(z[1]) * cst[m] + sigf(z[0]) * tanhf2(z[2]);
                    cst[m] = cc;
                    hv[m] = f2bf(sigf(z[3]) * tanhf2(cc));
                }
                const int off = (((t & 3) * 2 + mg) * 16 + cs) * 2048 + bl * 64 + jj * 8;
                stq8(rh0, off, hv[0], hv[1], hv[2], hv[3]);
            }
            __syncthreads();   // drain stores (vmcnt(0) before barrier)
            if (tid == 0) publish(ctrl, G_S0D, t, sub);
        }
    } else if (blk < 96) {
        // ------- S1: lstm1, split-phase.
        // early deps: S0d[t], SAd[t]; WAR: S2r[t-4]. late dep: S1d[t-1].
        // LDS row (stride 2256): h0[0..511] | win96[512..607] | h1prev[608..1119] | pad
        const int q = blk - 32, cs = q >> 1, mg = q & 1;
        const int mb = mg * 8, sub = mb + (cs & 7);
        __amdgpu_buffer_rsrc_t rh0 = mkrsrc(h0b);
        __amdgpu_buffer_rsrc_t rw  = mkrsrc(winb);
        __amdgpu_buffer_rsrc_t rh1 = mkrsrc(h1b);
        u16*   aL  = (u16*)smem;                   // 32 rows x 2256B
        float* zb  = (float*)(smem + 72192);       // 32 x 68
        float* b1s = (float*)(smem + 80896);       // 64
        if (tid < 64) b1s[tid] = b1[(tid >> 4) * 512 + cs * 16 + (tid & 15)];
        v8s bw[35];
        {
            const int cn = wave * 512 + cs * 16 + l15;
            #pragma unroll
            for (int kc = 0; kc < 35; kc++)
                #pragma unroll
                for (int j = 0; j < 8; j++) {
                    const int k = kc * 32 + quad * 8 + j;
                    short v = 0;
                    if (kc < 19) { if (k < 595) v = f2bfs(W1[k * 2048 + cn]); }
                    else v = f2bfs(U1[(k - 608) * 2048 + cn]);
                    bw[kc][j] = v;
                }
        }
        float cst[2] = {0.f, 0.f};
        __syncthreads();
        #pragma unroll 1
        for (int t = 0; t < TT; t++) {
            wait4(ctrl, G_S0D, t, 32, mb, G_SAD, t, 16, mb, G_S2R, t - 4, 64, mb, -1, 0, 0, 0);
            {   // EARLY stage: h0[t] (16x2KB packed) + win[t] (32 rows x 192B)
                const int baseH = (((t & 3) * 2 + mg) * 16) * 2048;
                const int baseW = (((t & 3) * 2 + mg) * 32) * 256;
                #pragma unroll
                for (int c8 = 0; c8 < 8; c8++) {
                    const int c = tid + 256 * c8;
                    const int cs_ = c >> 7, w = c & 127;
                    const int row = w >> 2, col16 = w & 3;
                    v4u d = ldu4(rh0, baseH + cs_ * 2048 + w * 16);
                    *(v4u*)((char*)aL + row * 2256 + cs_ * 64 + col16 * 16) = d;
                }
                #pragma unroll
                for (int c2 = 0; c2 < 2; c2++) {
                    const int c = tid + 256 * c2;
                    if (c < 384) {
                        const int row = c / 12, off = c - row * 12;
                        v4u d = ldu4(rw, baseW + row * 256 + off * 16);
                        *(v4u*)((char*)aL + row * 2256 + 1024 + off * 16) = d;
                    }
                }
            }
            __syncthreads();
            if (tid == 0) publish(ctrl, G_S1R, t, sub);   // h0/win slot read-done
            // LATE wait: own recurrence only
            wait4(ctrl, G_S1D, t - 1, 64, mb, -1, 0, 0, 0, -1, 0, 0, 0, -1, 0, 0, 0);
            {   // LATE stage: h1[t-1] (32x1KB packed)
                const int baseP = ((((t + 3) & 3) * 2 + mg) * 32) * 1024;
                #pragma unroll
                for (int c8 = 0; c8 < 8; c8++) {
                    const int c = tid + 256 * c8;
                    const int cs_ = c >> 6, w = c & 63;
                    const int row = w >> 1, col16 = w & 1;
                    v4u d = ldu4(rh1, baseP + cs_ * 1024 + w * 16);
                    *(v4u*)((char*)aL + row * 2256 + 1216 + cs_ * 32 + col16 * 16) = d;
                }
            }
            // EARLY MFMAs (cols 0..607) overlap the late loads in flight
            v4f c0 = {0,0,0,0}, c1 = {0,0,0,0};
            const int xo = quad * 16;
            #pragma unroll
            for (int kc = 0; kc < 19; kc++) {
                v8s x0 = *(const v8s*)((const char*)aL + l15 * 2256 + kc * 64 + xo);
                v8s x1 = *(const v8s*)((const char*)aL + (16 + l15) * 2256 + kc * 64 + xo);
                c0 = MFMA16(x0, bw[kc], c0, 0, 0, 0);
                c1 = MFMA16(x1, bw[kc], c1, 0, 0, 0);
            }
            __syncthreads();
            // LATE MFMAs (h1prev cols 608..1119)
            #pragma unroll
            for (int kc = 19; kc < 35; kc++) {
                v8s x0 = *(const v8s*)((const char*)aL + l15 * 2256 + kc * 64 + xo);
                v8s x1 = *(const v8s*)((const char*)aL + (16 + l15) * 2256 + kc * 64 + xo);
                c0 = MFMA16(x0, bw[kc], c0, 0, 0, 0);
                c1 = MFMA16(x1, bw[kc], c1, 0, 0, 0);
            }
            #pragma unroll
            for (int r = 0; r < 4; r++) {
                zb[(quad * 4 + r) * 68 + wave * 17 + l15] = c0[r];
                zb[(16 + quad * 4 + r) * 68 + wave * 17 + l15] = c1[r];
            }
            __syncthreads();
            {   // epilogue: write h1[t] ONCE into own packed 1KB chunk
                const int bl = tid & 31, jj = tid >> 5;
                u16 hv[2];
                #pragma unroll
                for (int m = 0; m < 2; m++) {
                    const int j = jj * 2 + m;
                    float z[4];
                    #pragma unroll
                    for (int g = 0; g < 4; g++)
                        z[g] = zb[bl * 68 + g * 17 + j] + b1s[g * 16 + j];
                    const float cc = sigf(z[1]) * cst[m] + sigf(z[0]) * tanhf2(z[2]);
                    cst[m] = cc;
                    hv[m] = f2bf(sigf(z[3]) * tanhf2(cc));
                }
                const int off = (((t & 3) * 2 + mg) * 32 + cs) * 1024 + bl * 32 + jj * 4;
                stq4(rh1, off, hv[0], hv[1]);
            }
            __syncthreads();
            if (tid == 0) publish(ctrl, G_S1D, t, sub);
        }
    } else if (blk < 160) {
        // ------- S2: lstm2, split-phase. early dep: S1d[t]; WAR: SMr[t-4]. late dep: S2d[t-1].
        const int q = blk - 96, cs = q >> 1, mg = q & 1;
        const int mb = mg * 8, sub = mb + (cs & 7);
        __amdgpu_buffer_rsrc_t rh1 = mkrsrc(h1b);
        __amdgpu_buffer_rsrc_t rh2 = mkrsrc(h2b);
        u16*   aL  = (u16*)smem;                   // 32 rows x 2064B
        float* zb  = (float*)(smem + 66048);       // 32 x 68
        float* b2s = (float*)(smem + 74752);       // 64
        if (tid < 64) b2s[tid] = b2[(tid >> 4) * 512 + cs * 16 + (tid & 15)];
        v8s bw[32];
        {
            const int cn = wave * 512 + cs * 16 + l15;
            #pragma unroll
            for (int kc = 0; kc < 32; kc++)
                #pragma unroll
                for (int j = 0; j < 8; j++) {
                    const int k = kc * 32 + quad * 8 + j;
                    bw[kc][j] = (k < 512) ? f2bfs(W2[k * 2048 + cn]) : f2bfs(U2[(k - 512) * 2048 + cn]);
                }
        }
        float cst[2] = {0.f, 0.f};
        __syncthreads();
        #pragma unroll 1
        for (int t = 0; t < TT; t++) {
            wait4(ctrl, G_S1D, t, 64, mb, G_SMR, t - 4, 2, mb, -1, 0, 0, 0, -1, 0, 0, 0);
            {   // EARLY stage: h1[t] (32x1KB packed) -> LDS cols [0,512)
                const int baseP = (((t & 3) * 2 + mg) * 32) * 1024;
                #pragma unroll
                for (int c8 = 0; c8 < 8; c8++) {
                    const int c = tid + 256 * c8;
                    const int cs_ = c >> 6, w = c & 63;
                    const int row = w >> 1, col16 = w & 1;
                    v4u d = ldu4(rh1, baseP + cs_ * 1024 + w * 16);
                    *(v4u*)((char*)aL + row * 2064 + cs_ * 32 + col16 * 16) = d;
                }
            }
            __syncthreads();
            if (tid == 0) publish(ctrl, G_S2R, t, sub);   // h1 slot read-done
            wait4(ctrl, G_S2D, t - 1, 64, mb, -1, 0, 0, 0, -1, 0, 0, 0, -1, 0, 0, 0);
            {   // LATE stage: h2[t-1] (32x1KB packed) -> LDS cols [512,1024)
                const int baseP = ((((t + 3) & 3) * 2 + mg) * 32) * 1024;
                #pragma unroll
                for (int c8 = 0; c8 < 8; c8++) {
                    const int c = tid + 256 * c8;
                    const int cs_ = c >> 6, w = c & 63;
                    const int row = w >> 1, col16 = w & 1;
                    v4u d = ldu4(rh2, baseP + cs_ * 1024 + w * 16);
                    *(v4u*)((char*)aL + row * 2064 + 1024 + cs_ * 32 + col16 * 16) = d;
                }
            }
            // EARLY MFMAs overlap late loads
            v4f c0 = {0,0,0,0}, c1 = {0,0,0,0};
            const int xo = quad * 16;
            #pragma unroll
            for (int kc = 0; kc < 16; kc++) {
                v8s x0 = *(const v8s*)((const char*)aL + l15 * 2064 + kc * 64 + xo);
                v8s x1 = *(const v8s*)((const char*)aL + (16 + l15) * 2064 + kc * 64 + xo);
                c0 = MFMA16(x0, bw[kc], c0, 0, 0, 0);
                c1 = MFMA16(x1, bw[kc], c1, 0, 0, 0);
            }
            __syncthreads();
            // LATE MFMAs
            #pragma unroll
            for (int kc = 16; kc < 32; kc++) {
                v8s x0 = *(const v8s*)((const char*)aL + l15 * 2064 + kc * 64 + xo);
                v8s x1 = *(const v8s*)((const char*)aL + (16 + l15) * 2064 + kc * 64 + xo);
                c0 = MFMA16(x0, bw[kc], c0, 0, 0, 0);
                c1 = MFMA16(x1, bw[kc], c1, 0, 0, 0);
            }
            #pragma unroll
            for (int r = 0; r < 4; r++) {
                zb[(quad * 4 + r) * 68 + wave * 17 + l15] = c0[r];
                zb[(16 + quad * 4 + r) * 68 + wave * 17 + l15] = c1[r];
            }
            __syncthreads();
            {   // epilogue: write h2[t] into own packed 1KB chunk
                const int bl = tid & 31, jj = tid >> 5;
                u16 hv[2];
                #pragma unroll
                for (int m = 0; m < 2; m++) {
                    const int j = jj * 2 + m;
                    float z[4];
                    #pragma unroll
                    for (int g = 0; g < 4; g++)
                        z[g] = zb[bl * 68 + g * 17 + j] + b2s[g * 16 + j];
                    const float cc = sigf(z[1]) * cst[m] + sigf(z[0]) * tanhf2(z[2]);
                    cst[m] = cc;
                    hv[m] = f2bf(sigf(z[3]) * tanhf2(cc));
                }
                const int off = (((t & 3) * 2 + mg) * 32 + cs) * 1024 + bl * 32 + jj * 4;
                stq4(rh2, off, hv[0], hv[1]);
            }
            __syncthreads();
            if (tid == 0) publish(ctrl, G_S2D, t, sub);
        }
    } else if (blk < 176) {
        // ------- SA: attention. deps: S0d[t]; WAR: S1r[t-4]. One batch per wave.
        const int a = blk - 160;
        const int mg = a >> 3, mb = mg * 8, sub = mb + (a & 7);
        const int b = a * 4 + wave;
        const int rloc = (a & 7) * 4 + wave;     // row within mg
        __amdgpu_buffer_rsrc_t rh0 = mkrsrc(h0b);
        __amdgpu_buffer_rsrc_t rw  = mkrsrc(winb);
        u16*   watl = (u16*)smem;                      // 32 x 520 u16
        u16*   hrow = (u16*)(smem + 33280);            // 4 x 520 u16
        float* phis = (float*)(smem + 37440);          // 4 x 80
        u16*   idxs = (u16*)(smem + 38720);            // 4 x 80
        {
            #pragma unroll
            for (int c8 = 0; c8 < 8; c8++) {
                const int c = tid + 256 * c8;
                const int row = c >> 6, off = c & 63;
                *(v4u*)((char*)watl + row * 1040 + off * 16) = *(const v4u*)(WaT + row * 512 + off * 8);
            }
        }
        #pragma unroll
        for (int rep = 0; rep < 2; rep++) {
            const int u = rep * 64 + lane;
            if (u < 80) {
                int c = 0;
                #pragma unroll 1
                for (int cc = 0; cc < 80; cc++)
                    if (charseq[b * 6400 + u * 80 + cc] > 0.5f) c = cc;
                idxs[wave * 80 + u] = (u16)c;
            }
        }
        float kap = (lane < 10) ? kappa0[b * 10 + lane] : 0.f;
        const float baf = (lane < 30) ? ba[lane] : 0.f;
        const int nn = lane & 31;
        const int k0 = (lane >> 5) * 256;
        const u16* wrow = watl + nn * 520 + k0;
        __syncthreads();
        #pragma unroll 1
        for (int t = 0; t < TT; t++) {
            float sx0 = 0.f, sx1 = 0.f;
            if (lane == 40) { sx0 = stroke[(b * TT + t) * 3 + 0]; sx1 = stroke[(b * TT + t) * 3 + 1]; }
            else if (lane == 41) { sx0 = stroke[(b * TT + t) * 3 + 2]; }
            wait4(ctrl, G_S0D, t, 32, mb, G_S1R, t - 4, 64, mb, -1, 0, 0, 0, -1, 0, 0, 0);
            {   // stage 4 h0[t] rows from packed chunks (row r -> 16 x 64B pieces)
                const int base = (((t & 3) * 2 + mg) * 16) * 2048;
                const int row = tid >> 6, q6 = tid & 63;
                const int cs_ = q6 >> 2, col16 = q6 & 3;
                const int rl = (a & 7) * 4 + row;
                v4u d = ldu4(rh0, base + cs_ * 2048 + rl * 64 + col16 * 16);
                *(v4u*)((char*)hrow + row * 1040 + cs_ * 64 + col16 * 16) = d;
            }
            __syncthreads();
            if (tid == 0) publish(ctrl, G_SAR, t, sub);
            float acc = 0.f;
            #pragma unroll
            for (int kk = 0; kk < 32; kk++) {
                v8s hv = *(const v8s*)((const char*)hrow + wave * 1040 + (k0 + kk * 8) * 2);
                v8s wv = *(const v8s*)(wrow + kk * 8);
                #pragma unroll
                for (int e = 0; e < 8; e++) acc += bf2f((u16)hv[e]) * bf2f((u16)wv[e]);
            }
            acc += __shfl_xor(acc, 32);
            const float abk = __expf(acc + baf);
            const float kofv = __shfl(abk, 20 + (lane < 10 ? lane : 0));
            if (lane < 10) kap += kofv;
            const float u1f = (float)lane;
            float p1 = 0.f, p2 = 0.f;
            #pragma unroll
            for (int kk = 0; kk < 10; kk++) {
                const float al = __shfl(abk, kk);
                const float be = __shfl(abk, 10 + kk);
                const float kp = __shfl(kap, kk);
                const float d1 = kp - u1f, d2 = kp - (u1f + 64.f);
                p1 += al * __expf(-be * d1 * d1);
                p2 += al * __expf(-be * d2 * d2);
            }
            phis[wave * 80 + lane] = p1;
            if (lane < 16) phis[wave * 80 + 64 + lane] = p2;
            __syncthreads();
            // write win[t] row: 256B fully owned by this wave (cols 83..95 zeroed)
            const int db = (((t & 3) * 2 + mg) * 32 + rloc) * 256;
            if (lane < 40) {
                const int c0 = 2 * lane;
                float w0 = 0.f, w1 = 0.f;
                #pragma unroll 1
                for (int u = 0; u < 80; u++) {
                    const float pv = phis[wave * 80 + u];
                    const int ix = (int)idxs[wave * 80 + u];
                    w0 += (ix == c0)     ? pv : 0.f;
                    w1 += (ix == c0 + 1) ? pv : 0.f;
                }
                stq4(rw, db + c0 * 2, f2bf(w0), f2bf(w1));
            } else if (lane == 40) {
                stq4(rw, db + 160, f2bf(sx0), f2bf(sx1));
            } else if (lane == 41) {
                stq4(rw, db + 164, f2bf(sx0), (u16)0);
            } else if (lane < 48) {
                stq4(rw, db + 168 + (lane - 42) * 4, (u16)0, (u16)0);
            }
            __syncthreads();
            if (tid == 0) publish(ctrl, G_SAD, t, sub);
        }
    } else {
        // ------- SM: MDN head. deps: S2d[t] (same mg). 2 blocks.
        const int mgs = blk - 176;
        const int mb = mgs * 8, sub = mb;
        __amdgpu_buffer_rsrc_t rh2 = mkrsrc(h2b);
        u16*   aL = (u16*)smem;                    // 32 rows x 1040B
        float* zb = (float*)(smem + 33280);        // 32 x 132
        v8s bw0[16], bw1[16];
        {
            const int nA = wave * 32 + l15, nB = nA + 16;
            #pragma unroll
            for (int kc = 0; kc < 16; kc++)
                #pragma unroll
                for (int j = 0; j < 8; j++) {
                    const int k = kc * 32 + quad * 8 + j;
                    bw0[kc][j] = (nA < 121) ? f2bfs(Wm[k * 121 + nA]) : (short)0;
                    bw1[kc][j] = (nB < 121) ? f2bfs(Wm[k * 121 + nB]) : (short)0;
                }
        }
        __syncthreads();
        #pragma unroll 1
        for (int t = 0; t < TT; t++) {
            wait4(ctrl, G_S2D, t, 64, mb, -1, 0, 0, 0, -1, 0, 0, 0, -1, 0, 0, 0);
            {   // stage h2[t] (32x1KB packed)
                const int baseP = (((t & 3) * 2 + mgs) * 32) * 1024;
                #pragma unroll
                for (int c8 = 0; c8 < 8; c8++) {
                    const int c = tid + 256 * c8;
                    const int cs_ = c >> 6, w = c & 63;
                    const int row = w >> 1, col16 = w & 1;
                    v4u d = ldu4(rh2, baseP + cs_ * 1024 + w * 16);
                    *(v4u*)((char*)aL + row * 1040 + cs_ * 32 + col16 * 16) = d;
                }
            }
            __syncthreads();
            if (tid == 0) publish(ctrl, G_SMR, t, sub);
            v4f c0a = {0,0,0,0}, c0b = {0,0,0,0}, c1a = {0,0,0,0}, c1b = {0,0,0,0};
            const int xo = quad * 16;
            #pragma unroll
            for (int kc = 0; kc < 16; kc++) {
                v8s x0 = *(const v8s*)((const char*)aL + l15 * 1040 + kc * 64 + xo);
                v8s x1 = *(const v8s*)((const char*)aL + (16 + l15) * 1040 + kc * 64 + xo);
                c0a = MFMA16(x0, bw0[kc], c0a, 0, 0, 0);
                c1a = MFMA16(x0, bw1[kc], c1a, 0, 0, 0);
                c0b = MFMA16(x1, bw0[kc], c0b, 0, 0, 0);
                c1b = MFMA16(x1, bw1[kc], c1b, 0, 0, 0);
            }
            const int n0 = wave * 32 + l15, n1 = n0 + 16;
            #pragma unroll
            for (int r = 0; r < 4; r++) {
                zb[(quad * 4 + r) * 132 + n0] = c0a[r];
                zb[(quad * 4 + r) * 132 + n1] = c1a[r];
                zb[(16 + quad * 4 + r) * 132 + n0] = c0b[r];
                zb[(16 + quad * 4 + r) * 132 + n1] = c1b[r];
            }
            __syncthreads();
            {
                const int b8 = tid >> 3, g8 = tid & 7;
                const int b = mgs * 32 + b8;
                const float* zr = zb + b8 * 132;
                float* orow = out + ((size_t)(b * TT + t)) * 121;
                if (g8 == 0) {
                    orow[0] = sigf(-(zr[0] + bm[0]));
                    float mx = -1e30f;
                    float zv[20];
                    #pragma unroll 1
                    for (int nl = 1; nl <= 20; nl++) { zv[nl - 1] = zr[nl] + bm[nl]; mx = fmaxf(mx, zv[nl - 1]); }
                    float ss = 0.f;
                    #pragma unroll 1
                    for (int nl = 0; nl < 20; nl++) { zv[nl] = __expf(zv[nl] - mx); ss += zv[nl]; }
                    const float inv = 1.f / ss;
                    #pragma unroll 1
                    for (int nl = 0; nl < 20; nl++) orow[nl + 1] = zv[nl] * inv;
                } else if (g8 <= 2) {
                    const int s0 = 21 + (g8 - 1) * 20;
                    #pragma unroll 1
                    for (int nl = s0; nl < s0 + 20; nl++) orow[nl] = zr[nl] + bm[nl];
                } else if (g8 <= 4) {
                    const int s0 = 61 + (g8 - 3) * 20;
                    #pragma unroll 1
                    for (int nl = s0; nl < s0 + 20; nl++) orow[nl] = __expf(zr[nl] + bm[nl]);
                } else if (g8 <= 6) {
                    const int s0 = 101 + (g8 - 5) * 10;
                    #pragma unroll 1
                    for (int nl = s0; nl < s0 + 10; nl++) orow[nl] = tanhf2(zr[nl] + bm[nl]);
                }
            }
            __syncthreads();
        }
    }
}

extern "C" void kernel_launch(void* const* d_in, const int* in_sizes, int n_in,
                              void* d_out, int out_size, void* d_ws, size_t ws_size,
                              hipStream_t stream) {
    const float* stroke  = (const float*)d_in[0];
    const float* charseq = (const float*)d_in[1];
    const float* kappa0  = (const float*)d_in[2];
    const float* W0 = (const float*)d_in[3];
    const float* U0 = (const float*)d_in[4];
    const float* b0 = (const float*)d_in[5];
    const float* W1 = (const float*)d_in[6];
    const float* U1 = (const float*)d_in[7];
    const float* b1 = (const float*)d_in[8];
    const float* W2 = (const float*)d_in[9];
    const float* U2 = (const float*)d_in[10];
    const float* b2 = (const float*)d_in[11];
    const float* Wa = (const float*)d_in[12];
    const float* ba = (const float*)d_in[13];
    const float* Wm = (const float*)d_in[14];
    const float* bm = (const float*)d_in[15];
    char* ws = (char*)d_ws;

    static bool attr_done = false;
    if (!attr_done) {
        hipFuncSetAttribute((const void*)hw_main,
                            hipFuncAttributeMaxDynamicSharedMemorySize, SMEM_BYTES);
        attr_done = true;
    }

    hipMemsetAsync(d_ws, 0, WS_ZERO, stream);
    wat_init<<<8, 256, 0, stream>>>(Wa, (u16*)(ws + WAT_OFF));
    hw_main<<<NBLK, 256, SMEM_BYTES, stream>>>(stroke, charseq, kappa0, W0, U0, b0,
                                               W1, U1, b1, W2, U2, b2, ba, Wm, bm,
                                               (float*)d_out, ws);
}